// Round 1
// baseline (1355.871 us; speedup 1.0000x reference)
//
#include <hip/hip_runtime.h>

#define TT    8
#define LLAY  2
#define BB    512
#define MM    128
#define EE    512
#define NH    8
#define HID   1024
#define NA    16
#define NOBS  64

// ---- output layout (float offsets): logits [B,A], values [B], memory_out [B,L,E]
#define OUT_LOGITS 0
#define OUT_VALUES (BB*NA)
#define OUT_MEM    (BB*NA + BB)

// ---- workspace layout (float offsets); requires ws_size >= ~32 MB ----
#define WS_H    0
#define WS_QN   (WS_H   + BB*EE)
#define WS_Q    (WS_QN  + BB*EE)
#define WS_HN   (WS_Q   + BB*EE)
#define WS_F1   (WS_HN  + BB*EE)
#define WS_O    (WS_F1  + BB*EE)
#define WS_Z1A  (WS_O   + BB*EE)
#define WS_Z2A  (WS_Z1A + BB*HID)
#define WS_Z1C  (WS_Z2A + BB*HID)
#define WS_Z2C  (WS_Z1C + BB*HID)
#define WS_R    (WS_Z2C + BB*HID)
#define WS_PV   (WS_R   + BB*NH*EE)
#define WS_INT  (WS_PV  + BB*NH*EE)

// int offsets inside the WS_INT region (viewed as int*)
#define WI_CNT  0
#define WI_OFF  8
#define WI_MODE 17
#define WI_ROWL 32

#define DPP_ADD(x, ctrl) \
  (x) += __int_as_float(__builtin_amdgcn_update_dpp(0, __float_as_int(x), (ctrl), 0xf, 0xf, true))

// full wave64 sum, result broadcast to all lanes.
// row_ror rotations (bijective within 16-lane rows) -> per-row totals in every
// lane, then two shfl_xor steps combine the 4 rows.
__device__ __forceinline__ float wave_sum(float x) {
  DPP_ADD(x, 0x121);  // row_ror:1
  DPP_ADD(x, 0x122);  // row_ror:2
  DPP_ADD(x, 0x124);  // row_ror:4
  DPP_ADD(x, 0x128);  // row_ror:8
  x += __shfl_xor(x, 16);
  x += __shfl_xor(x, 32);
  return x;
}

__device__ __forceinline__ float f4c(const float4 v, int c) {
  return c == 0 ? v.x : (c == 1 ? v.y : (c == 2 ? v.z : v.w));
}

// ---------------------------------------------------------------- prep
// task grouping (counts / offsets / row lists) + mask dtype probe.
__global__ __launch_bounds__(256) void prep_k(const int* __restrict__ skills,
                                              const void* __restrict__ mask,
                                              int* __restrict__ wsI)
{
  __shared__ int cnt_s[TT];
  __shared__ int off_s[TT];
  const int tid = threadIdx.x;
  if (tid < TT) cnt_s[tid] = 0;
  __syncthreads();
  const int b0 = tid, b1i = tid + 256;
  const int t0 = skills[b0], t1 = skills[b1i];
  const int o0 = atomicAdd(&cnt_s[t0], 1);
  const int o1 = atomicAdd(&cnt_s[t1], 1);
  __syncthreads();
  if (tid == 0) {
    int off = 0;
    for (int t = 0; t < TT; ++t) {
      off_s[t] = off;
      wsI[WI_CNT + t] = cnt_s[t];
      wsI[WI_OFF + t] = off;
      off += cnt_s[t];
    }
    // mask dtype probe: numpy bool (1B) vs int32 vs float32 (all-ones input)
    const unsigned char* m8 = (const unsigned char*)mask;
    const int w0 = *(const int*)mask;
    int mode = 0;
    if (m8[0] == 1 && m8[1] == 1 && m8[2] == 1 && m8[3] == 1) mode = 0;
    else if (w0 == 1) mode = 1;
    else if (w0 == 0x3f800000) mode = 2;
    wsI[WI_MODE] = mode;
  }
  __syncthreads();
  wsI[WI_ROWL + off_s[t0] + o0] = b0;
  wsI[WI_ROWL + off_s[t1] + o1] = b1i;
}

// ---------------------------------------------------------------- layernorm
template<bool MEMOUT>
__global__ __launch_bounds__(256) void ln_k(const float* __restrict__ src,
                                            float* __restrict__ dst,
                                            const float* __restrict__ sp,
                                            const float* __restrict__ bp,
                                            const int* __restrict__ skills,
                                            float* __restrict__ memout, int l)
{
  const int b = blockIdx.x, tid = threadIdx.x;
  const int t = skills[b];
  const float x0 = src[(size_t)b*EE + tid];
  const float x1 = src[(size_t)b*EE + tid + 256];
  if (MEMOUT) {
    memout[((size_t)b*LLAY + l)*EE + tid] = x0;
    memout[((size_t)b*LLAY + l)*EE + tid + 256] = x1;
  }
  __shared__ float rs[4], rq[4];
  float s = wave_sum(x0 + x1);
  float q = wave_sum(x0*x0 + x1*x1);
  const int wvi = tid >> 6, lane = tid & 63;
  if (lane == 0) { rs[wvi] = s; rq[wvi] = q; }
  __syncthreads();
  const float S = rs[0] + rs[1] + rs[2] + rs[3];
  const float Q = rq[0] + rq[1] + rq[2] + rq[3];
  const float mu = S * (1.f/EE);
  const float inv = rsqrtf(Q*(1.f/EE) - mu*mu + 1e-6f);
  const size_t pb = ((size_t)t*LLAY + l)*EE;
  dst[(size_t)b*EE + tid]       = (x0 - mu)*inv*sp[pb + tid]       + bp[pb + tid];
  dst[(size_t)b*EE + tid + 256] = (x1 - mu)*inv*sp[pb + tid + 256] + bp[pb + tid + 256];
}

// ---------------------------------------------------------------- grouped GEMM
// C[row, j] = act(A[row,:] @ W[task] + bias) (+res). rows gathered by task.
// tile: 16 rows x 256 cols, K chunked by 32. block 256 = 128 j-lanes x 2 rgrp.
template<bool RELU, bool HASBIAS, bool HASRES>
__global__ __launch_bounds__(256) void g1_k(const float* __restrict__ Aw, int lda,
                                            const float* __restrict__ W, size_t wStride, size_t wOff,
                                            int K, int J,
                                            const float* __restrict__ bias, int bStride, int bOff,
                                            const float* __restrict__ res, int ldres,
                                            float* __restrict__ C, int ldc,
                                            const int* __restrict__ wsI)
{
  const int t = blockIdx.z;
  const int cnt = wsI[WI_CNT + t];
  if (cnt == 0) return;
  const int off = wsI[WI_OFF + t];
  const int* rowl = wsI + WI_ROWL + off;
  const int tid = threadIdx.x;
  const int jl = tid & 127, rgrp = tid >> 7;
  const int jbase = blockIdx.x * 256;
  const float* Wt = W + (size_t)t*wStride + wOff;

  __shared__ __align__(16) float At[16*36];
  __shared__ float Wl[32*260];   // [kk][jj] -> conflict-free lane-consecutive reads
  __shared__ int rows_s[16];

  for (int rb = blockIdx.y*16; rb < cnt; rb += 128) {
    __syncthreads();
    if (tid < 16) rows_s[tid] = rowl[min(rb + tid, cnt - 1)];
    float acc[8][2];
    #pragma unroll
    for (int rr = 0; rr < 8; ++rr) { acc[rr][0] = 0.f; acc[rr][1] = 0.f; }
    for (int k0 = 0; k0 < K; k0 += 32) {
      __syncthreads();
      {
        const int rr = tid >> 4, kk2 = (tid & 15)*2;
        *(float2*)&At[rr*36 + kk2] =
            *(const float2*)(Aw + (size_t)rows_s[rr]*lda + k0 + kk2);
      }
      #pragma unroll 8
      for (int kk = 0; kk < 32; ++kk)
        Wl[kk*260 + tid] = Wt[(size_t)(k0 + kk)*J + jbase + tid];
      __syncthreads();
      #pragma unroll
      for (int k4 = 0; k4 < 32; k4 += 4) {
        float4 a[8];
        #pragma unroll
        for (int rr = 0; rr < 8; ++rr)
          a[rr] = *(const float4*)&At[(rgrp*8 + rr)*36 + k4];
        #pragma unroll
        for (int c = 0; c < 4; ++c) {
          const float w0 = Wl[(k4 + c)*260 + jl];
          const float w1 = Wl[(k4 + c)*260 + jl + 128];
          #pragma unroll
          for (int rr = 0; rr < 8; ++rr) {
            const float av = f4c(a[rr], c);
            acc[rr][0] += av*w0;
            acc[rr][1] += av*w1;
          }
        }
      }
    }
    #pragma unroll
    for (int rr = 0; rr < 8; ++rr) {
      const int r = rb + rgrp*8 + rr;
      if (r < cnt) {
        const int row = rows_s[rgrp*8 + rr];
        #pragma unroll
        for (int c = 0; c < 2; ++c) {
          const int j = jbase + jl + c*128;
          float v = acc[rr][c];
          if (HASBIAS) v += bias[(size_t)t*bStride + bOff + j];
          if (RELU) v = fmaxf(v, 0.f);
          if (HASRES) v += res[(size_t)row*ldres + j];
          C[(size_t)row*ldc + j] = v;
        }
      }
    }
  }
}

// ---------------------------------------------------------------- R kernel
// R[b,h,e] = sum_d Wk[e, h*64+d] * q[b, h*64+d]
__global__ __launch_bounds__(256) void r_k(const float* __restrict__ q_ws,
                                           const float* __restrict__ Wk,
                                           float* __restrict__ R_ws,
                                           const int* __restrict__ wsI, int l)
{
  const int t = blockIdx.z;
  const int cnt = wsI[WI_CNT + t];
  if (cnt == 0) return;
  const int off = wsI[WI_OFF + t];
  const int* rowl = wsI + WI_ROWL + off;
  const int et = blockIdx.x >> 3, h = blockIdx.x & 7;
  const int tid = threadIdx.x;
  const int jl = tid & 63, rgrp = tid >> 6;
  const float* Wt = Wk + ((size_t)t*LLAY + l)*EE*EE;

  __shared__ __align__(16) float Qt[32*68];
  __shared__ float Wl[64*68];   // [d][e]
  __shared__ int rows_s[32];

  #pragma unroll 4
  for (int i = 0; i < 16; ++i) {
    const int lin = i*256 + tid;
    const int e = lin >> 6, d = lin & 63;
    Wl[d*68 + e] = Wt[(size_t)(et*64 + e)*EE + h*64 + d];
  }

  for (int rb = blockIdx.y*32; rb < cnt; rb += 128) {
    __syncthreads();
    if (tid < 32) rows_s[tid] = rowl[min(rb + tid, cnt - 1)];
    __syncthreads();
    {
      const int rr = tid >> 3, d8 = (tid & 7)*8;
      const float* qp = q_ws + (size_t)rows_s[rr]*EE + h*64 + d8;
      *(float4*)&Qt[rr*68 + d8]     = *(const float4*)qp;
      *(float4*)&Qt[rr*68 + d8 + 4] = *(const float4*)(qp + 4);
    }
    __syncthreads();
    float acc[8];
    #pragma unroll
    for (int rr = 0; rr < 8; ++rr) acc[rr] = 0.f;
    #pragma unroll
    for (int d4 = 0; d4 < 64; d4 += 4) {
      float4 a[8];
      #pragma unroll
      for (int rr = 0; rr < 8; ++rr)
        a[rr] = *(const float4*)&Qt[(rgrp*8 + rr)*68 + d4];
      #pragma unroll
      for (int c = 0; c < 4; ++c) {
        const float w = Wl[(d4 + c)*68 + jl];
        #pragma unroll
        for (int rr = 0; rr < 8; ++rr) acc[rr] += f4c(a[rr], c)*w;
      }
    }
    #pragma unroll
    for (int rr = 0; rr < 8; ++rr) {
      const int r = rb + rgrp*8 + rr;
      if (r < cnt)
        R_ws[((size_t)rows_s[rgrp*8 + rr]*NH + h)*EE + et*64 + jl] = acc[rr];
    }
  }
}

// ---------------------------------------------------------------- attention
// per (b,l): scores via low-rank R, masked online-normalized softmax with
// analytic LN folding; outputs normalized PV[b,h,e] = sum_m p*kn[m,e].
__global__ __launch_bounds__(256) void attn_k(const float* __restrict__ mem,
                                              const float* __restrict__ qn_ws,
                                              const float* __restrict__ R_ws,
                                              const float* __restrict__ ln1s,
                                              const float* __restrict__ ln1b,
                                              const void* __restrict__ mask,
                                              const int* __restrict__ skills,
                                              const int* __restrict__ wsI,
                                              float* __restrict__ PV, int l)
{
  const int b = blockIdx.x, tid = threadIdx.x;
  const int wvi = tid >> 6, lane = tid & 63;
  const int t = skills[b];
  const int mode = wsI[WI_MODE];

  __shared__ __align__(16) float qn_l[EE];
  __shared__ __align__(16) float w_s[NH][132];
  __shared__ float mu_s[MM], inv_s[MM];
  __shared__ float hsS[NH], hsA[NH], hsP[NH], hspex[NH];

  for (int i = tid; i < EE; i += 256) qn_l[i] = qn_ws[(size_t)b*EE + i];

  const int e8 = lane*8;
  const float* s1p = ln1s + ((size_t)t*LLAY + l)*EE;
  const float* b1p = ln1b + ((size_t)t*LLAY + l)*EE;
  float s1v[8], b1v[8], qnv[8];
  *(float4*)&s1v[0] = *(const float4*)(s1p + e8);
  *(float4*)&s1v[4] = *(const float4*)(s1p + e8 + 4);
  *(float4*)&b1v[0] = *(const float4*)(b1p + e8);
  *(float4*)&b1v[4] = *(const float4*)(b1p + e8 + 4);
  *(float4*)&qnv[0] = *(const float4*)(qn_ws + (size_t)b*EE + e8);
  *(float4*)&qnv[4] = *(const float4*)(qn_ws + (size_t)b*EE + e8 + 4);

  const float scale = 0.125f;  // 1/sqrt(64)
  float rp[NH][8];
  float SR[NH], BR[NH], SE[NH];
  #pragma unroll
  for (int h = 0; h < NH; ++h) {
    float rv[8];
    *(float4*)&rv[0] = *(const float4*)(R_ws + ((size_t)b*NH + h)*EE + e8);
    *(float4*)&rv[4] = *(const float4*)(R_ws + ((size_t)b*NH + h)*EE + e8 + 4);
    float pr = 0.f, pb = 0.f, ps = 0.f;
    #pragma unroll
    for (int j = 0; j < 8; ++j) {
      const float r = rv[j]*scale;
      const float x = r*s1v[j];
      rp[h][j] = x;
      pr += x; pb += b1v[j]*r; ps += qnv[j]*r;
    }
    SR[h] = wave_sum(pr);
    BR[h] = wave_sum(pb);
    SE[h] = wave_sum(ps);  // extra-row score (kn==qn)
  }

  // phase A: stream memory rows, score = inv*dot(x,Rp) - mu*inv*SR + BR
  for (int m = wvi; m < MM; m += 4) {
    const float* rowp = mem + (((size_t)b*LLAY + l)*MM + m)*EE;
    float xv[8];
    *(float4*)&xv[0] = *(const float4*)(rowp + e8);
    *(float4*)&xv[4] = *(const float4*)(rowp + e8 + 4);
    float s = 0.f, q = 0.f;
    #pragma unroll
    for (int j = 0; j < 8; ++j) { s += xv[j]; q += xv[j]*xv[j]; }
    const float S = wave_sum(s);
    const float Q = wave_sum(q);
    const float muv = S*(1.f/EE);
    const float invv = rsqrtf(Q*(1.f/EE) - muv*muv + 1e-6f);
    float dd[NH];
    #pragma unroll
    for (int h = 0; h < NH; ++h) {
      float a = 0.f;
      #pragma unroll
      for (int j = 0; j < 8; ++j) a += xv[j]*rp[h][j];
      dd[h] = wave_sum(a);
    }
    bool valid;
    if (mode == 0)      valid = ((const unsigned char*)mask)[(size_t)b*MM + m] != 0;
    else if (mode == 1) valid = ((const int*)mask)[(size_t)b*MM + m] != 0;
    else                valid = ((const float*)mask)[(size_t)b*MM + m] != 0.f;
    if (lane == 0) {
      mu_s[m] = muv; inv_s[m] = invv;
      #pragma unroll
      for (int h = 0; h < NH; ++h)
        w_s[h][m] = valid ? (invv*dd[h] - muv*invv*SR[h] + BR[h]) : -1e30f;
    }
  }
  if (tid == 0) {
    #pragma unroll
    for (int h = 0; h < NH; ++h) w_s[h][MM] = SE[h];
  }
  __syncthreads();

  // softmax per head over 129 entries; store weights p*inv for mem rows
  {
    const int h = tid >> 5, li = tid & 31;
    const float v0 = w_s[h][li], v1 = w_s[h][li+32], v2 = w_s[h][li+64], v3 = w_s[h][li+96];
    const float ve = (li == 0) ? w_s[h][MM] : -3e38f;
    float mx = fmaxf(fmaxf(fmaxf(v0, v1), fmaxf(v2, v3)), ve);
    #pragma unroll
    for (int o = 16; o; o >>= 1) mx = fmaxf(mx, __shfl_xor(mx, o));
    const float i0 = inv_s[li], i1 = inv_s[li+32], i2 = inv_s[li+64], i3 = inv_s[li+96];
    const float m0 = mu_s[li], m1 = mu_s[li+32], m2 = mu_s[li+64], m3 = mu_s[li+96];
    const float p0 = __expf(v0 - mx), p1 = __expf(v1 - mx);
    const float p2 = __expf(v2 - mx), p3 = __expf(v3 - mx);
    const float pe = (li == 0) ? __expf(ve - mx) : 0.f;
    float Sp = p0 + p1 + p2 + p3 + pe;
    float Ap = p0*m0*i0 + p1*m1*i1 + p2*m2*i2 + p3*m3*i3;
    float Pp = p0 + p1 + p2 + p3;
    w_s[h][li]    = p0*i0;
    w_s[h][li+32] = p1*i1;
    w_s[h][li+64] = p2*i2;
    w_s[h][li+96] = p3*i3;
    #pragma unroll
    for (int o = 16; o; o >>= 1) {
      Sp += __shfl_xor(Sp, o);
      Ap += __shfl_xor(Ap, o);
      Pp += __shfl_xor(Pp, o);
    }
    if (li == 0) { hsS[h] = Sp; hsA[h] = Ap; hsP[h] = Pp; hspex[h] = pe; }
  }
  __syncthreads();

  // phase B: U[h,e] = sum_m (p*inv)[m,h] * x[m,e]; fold LN terms, normalize
  const int e0 = wvi*128 + lane*2;
  const float s1x = s1p[e0], s1y = s1p[e0+1];
  const float b1x = b1p[e0], b1y = b1p[e0+1];
  const float qx = qn_l[e0], qy = qn_l[e0+1];
  float accx[NH], accy[NH];
  #pragma unroll
  for (int h = 0; h < NH; ++h) { accx[h] = 0.f; accy[h] = 0.f; }
  const float* bp2 = mem + ((size_t)b*LLAY + l)*MM*EE + e0;
  for (int m4 = 0; m4 < MM; m4 += 4) {
    float4 wv4[NH];
    #pragma unroll
    for (int h = 0; h < NH; ++h) wv4[h] = *(const float4*)&w_s[h][m4];
    #pragma unroll
    for (int c = 0; c < 4; ++c) {
      const float2 x2 = *(const float2*)(bp2 + (size_t)(m4 + c)*EE);
      #pragma unroll
      for (int h = 0; h < NH; ++h) {
        const float w = f4c(wv4[h], c);
        accx[h] += w*x2.x;
        accy[h] += w*x2.y;
      }
    }
  }
  #pragma unroll
  for (int h = 0; h < NH; ++h) {
    const float is = 1.f/hsS[h];
    const float px = (s1x*(accx[h] - hsA[h]) + b1x*hsP[h] + hspex[h]*qx)*is;
    const float py = (s1y*(accy[h] - hsA[h]) + b1y*hsP[h] + hspex[h]*qy)*is;
    *(float2*)(PV + ((size_t)b*NH + h)*EE + e0) = make_float2(px, py);
  }
}

// ---------------------------------------------------------------- V fold
// o[b, h*64+j] = sum_e PV[b,h,e] * Wv[e, h*64+j]
__global__ __launch_bounds__(128) void ofold_k(const float* __restrict__ PV,
                                               const float* __restrict__ Wv,
                                               float* __restrict__ o_ws,
                                               const int* __restrict__ wsI, int l)
{
  const int t = blockIdx.z;
  const int cnt = wsI[WI_CNT + t];
  if (cnt == 0) return;
  const int off = wsI[WI_OFF + t];
  const int* rowl = wsI + WI_ROWL + off;
  const int h = blockIdx.x;
  const int tid = threadIdx.x;
  const int jl = tid & 63, rgrp = tid >> 6;
  const float* Wt = Wv + ((size_t)t*LLAY + l)*EE*EE;

  __shared__ __align__(16) float At[32*36];
  __shared__ float Wl[32*68];
  __shared__ int rows_s[32];

  for (int rb = blockIdx.y*32; rb < cnt; rb += 128) {
    __syncthreads();
    if (tid < 32) rows_s[tid] = rowl[min(rb + tid, cnt - 1)];
    float acc[16];
    #pragma unroll
    for (int rr = 0; rr < 16; ++rr) acc[rr] = 0.f;
    for (int k0 = 0; k0 < EE; k0 += 32) {
      __syncthreads();
      {
        const int rr = tid >> 2, k8 = (tid & 3)*8;
        const float* ap = PV + ((size_t)rows_s[rr]*NH + h)*EE + k0 + k8;
        *(float4*)&At[rr*36 + k8]     = *(const float4*)ap;
        *(float4*)&At[rr*36 + k8 + 4] = *(const float4*)(ap + 4);
      }
      #pragma unroll 4
      for (int i = 0; i < 16; ++i) {
        const int lin = i*128 + tid;
        const int kk = lin >> 6, jj = lin & 63;
        Wl[kk*68 + jj] = Wt[(size_t)(k0 + kk)*EE + h*64 + jj];
      }
      __syncthreads();
      #pragma unroll
      for (int k4 = 0; k4 < 32; k4 += 4) {
        float4 a[16];
        #pragma unroll
        for (int rr = 0; rr < 16; ++rr)
          a[rr] = *(const float4*)&At[(rgrp*16 + rr)*36 + k4];
        #pragma unroll
        for (int c = 0; c < 4; ++c) {
          const float w = Wl[(k4 + c)*68 + jl];
          #pragma unroll
          for (int rr = 0; rr < 16; ++rr) acc[rr] += f4c(a[rr], c)*w;
        }
      }
    }
    #pragma unroll
    for (int rr = 0; rr < 16; ++rr) {
      const int r = rb + rgrp*16 + rr;
      if (r < cnt)
        o_ws[(size_t)rows_s[rgrp*16 + rr]*EE + h*64 + jl] = acc[rr];
    }
  }
}

// ---------------------------------------------------------------- head
__global__ __launch_bounds__(256) void head_k(const float* __restrict__ z2a,
                                              const float* __restrict__ z2c,
                                              const float* __restrict__ aW3,
                                              const float* __restrict__ ab3,
                                              const float* __restrict__ cW3,
                                              const float* __restrict__ cb3,
                                              const int* __restrict__ skills,
                                              float* __restrict__ out)
{
  const int b = blockIdx.x, tid = threadIdx.x;
  const int t = skills[b];
  __shared__ float za[HID], zc[HID];
  __shared__ float red[16][17];
  __shared__ float redv[4];
  for (int i = tid; i < HID; i += 256) {
    za[i] = z2a[(size_t)b*HID + i];
    zc[i] = z2c[(size_t)b*HID + i];
  }
  __syncthreads();
  {
    const int j = tid & 15, grp = tid >> 4;
    const float* w = aW3 + (size_t)t*HID*NA;
    float p = 0.f;
    for (int i = grp*64; i < grp*64 + 64; ++i) p += za[i]*w[(size_t)i*NA + j];
    red[grp][j] = p;
  }
  float pvv = 0.f;
  {
    const float* w = cW3 + (size_t)t*HID;
    for (int i = tid; i < HID; i += 256) pvv += zc[i]*w[i];
  }
  pvv = wave_sum(pvv);
  const int wvi = tid >> 6, lane = tid & 63;
  if (lane == 0) redv[wvi] = pvv;
  __syncthreads();
  if (tid < 16) {
    float v = ab3[(size_t)t*NA + tid];
    #pragma unroll
    for (int g = 0; g < 16; ++g) v += red[g][tid];
    out[OUT_LOGITS + (size_t)b*NA + tid] = v;
  }
  if (tid == 0)
    out[OUT_VALUES + b] = cb3[t] + redv[0] + redv[1] + redv[2] + redv[3];
}

// ---------------------------------------------------------------- launch
extern "C" void kernel_launch(void* const* d_in, const int* in_sizes, int n_in,
                              void* d_out, int out_size, void* d_ws, size_t ws_size,
                              hipStream_t stream)
{
  (void)in_sizes; (void)n_in; (void)out_size; (void)ws_size;
  const float* memories = (const float*)d_in[0];
  const float* obs   = (const float*)d_in[1];
  const float* We    = (const float*)d_in[2];
  const float* be    = (const float*)d_in[3];
  const float* Wq    = (const float*)d_in[4];
  const float* Wk    = (const float*)d_in[5];
  const float* Wv    = (const float*)d_in[6];
  const float* Wo    = (const float*)d_in[7];
  const float* bo    = (const float*)d_in[8];
  const float* W1    = (const float*)d_in[9];
  const float* b1    = (const float*)d_in[10];
  const float* W2    = (const float*)d_in[11];
  const float* b2    = (const float*)d_in[12];
  const float* ln1s  = (const float*)d_in[13];
  const float* ln1b  = (const float*)d_in[14];
  const float* ln2s  = (const float*)d_in[15];
  const float* ln2b  = (const float*)d_in[16];
  const float* aW1   = (const float*)d_in[17];
  const float* ab1   = (const float*)d_in[18];
  const float* aW2   = (const float*)d_in[19];
  const float* ab2   = (const float*)d_in[20];
  const float* aW3   = (const float*)d_in[21];
  const float* ab3   = (const float*)d_in[22];
  const float* cW1   = (const float*)d_in[23];
  const float* cb1   = (const float*)d_in[24];
  const float* cW2   = (const float*)d_in[25];
  const float* cb2   = (const float*)d_in[26];
  const float* cW3   = (const float*)d_in[27];
  const float* cb3   = (const float*)d_in[28];
  const int*   skills= (const int*)d_in[29];
  const void*  mask  = d_in[30];

  float* ws  = (float*)d_ws;
  float* out = (float*)d_out;
  float* h   = ws + WS_H;
  float* qn  = ws + WS_QN;
  float* q   = ws + WS_Q;
  float* hn  = ws + WS_HN;
  float* f1  = ws + WS_F1;
  float* o   = ws + WS_O;
  float* z1a = ws + WS_Z1A;
  float* z2a = ws + WS_Z2A;
  float* z1c = ws + WS_Z1C;
  float* z2c = ws + WS_Z2C;
  float* R   = ws + WS_R;
  float* PV  = ws + WS_PV;
  int*   wsI = (int*)(ws + WS_INT);

  prep_k<<<1, 256, 0, stream>>>(skills, mask, wsI);

  // h = obs @ We[t] + be[t]
  g1_k<false,true,false><<<dim3(2,8,8), 256, 0, stream>>>(
      obs, NOBS, We, (size_t)NOBS*EE, 0, NOBS, EE, be, EE, 0,
      nullptr, 0, h, EE, wsI);

  for (int l = 0; l < LLAY; ++l) {
    const size_t wOff = (size_t)l*EE*EE;
    ln_k<true><<<BB, 256, 0, stream>>>(h, qn, ln1s, ln1b, skills, out + OUT_MEM, l);
    g1_k<false,false,false><<<dim3(2,8,8), 256, 0, stream>>>(
        qn, EE, Wq, (size_t)LLAY*EE*EE, wOff, EE, EE, nullptr, 0, 0,
        nullptr, 0, q, EE, wsI);
    r_k<<<dim3(64,4,8), 256, 0, stream>>>(q, Wk, R, wsI, l);
    attn_k<<<BB, 256, 0, stream>>>(memories, qn, R, ln1s, ln1b, mask, skills, wsI, PV, l);
    ofold_k<<<dim3(8,4,8), 128, 0, stream>>>(PV, Wv, o, wsI, l);
    g1_k<false,true,true><<<dim3(2,8,8), 256, 0, stream>>>(
        o, EE, Wo, (size_t)LLAY*EE*EE, wOff, EE, EE, bo, LLAY*EE, l*EE,
        h, EE, h, EE, wsI);
    ln_k<false><<<BB, 256, 0, stream>>>(h, hn, ln2s, ln2b, skills, nullptr, l);
    g1_k<true,true,false><<<dim3(2,8,8), 256, 0, stream>>>(
        hn, EE, W1, (size_t)LLAY*EE*EE, wOff, EE, EE, b1, LLAY*EE, l*EE,
        nullptr, 0, f1, EE, wsI);
    g1_k<false,true,true><<<dim3(2,8,8), 256, 0, stream>>>(
        f1, EE, W2, (size_t)LLAY*EE*EE, wOff, EE, EE, b2, LLAY*EE, l*EE,
        h, EE, h, EE, wsI);
  }

  // actor / critic MLPs
  g1_k<true,true,false><<<dim3(4,8,8), 256, 0, stream>>>(
      h, EE, aW1, (size_t)EE*HID, 0, EE, HID, ab1, HID, 0, nullptr, 0, z1a, HID, wsI);
  g1_k<true,true,false><<<dim3(4,8,8), 256, 0, stream>>>(
      z1a, HID, aW2, (size_t)HID*HID, 0, HID, HID, ab2, HID, 0, nullptr, 0, z2a, HID, wsI);
  g1_k<true,true,false><<<dim3(4,8,8), 256, 0, stream>>>(
      h, EE, cW1, (size_t)EE*HID, 0, EE, HID, cb1, HID, 0, nullptr, 0, z1c, HID, wsI);
  g1_k<true,true,false><<<dim3(4,8,8), 256, 0, stream>>>(
      z1c, HID, cW2, (size_t)HID*HID, 0, HID, HID, cb2, HID, 0, nullptr, 0, z2c, HID, wsI);

  head_k<<<BB, 256, 0, stream>>>(z2a, z2c, aW3, ab3, cW3, cb3, skills, out);
}

// Round 2
// 577.440 us; speedup vs baseline: 2.3481x; 2.3481x over previous
//
#include <hip/hip_runtime.h>

#define TT    8
#define LLAY  2
#define BB    512
#define MM    128
#define EE    512
#define NH    8
#define HID   1024
#define NA    16
#define NOBS  64

// ---- output layout (float offsets): logits [B,A], values [B], memory_out [B,L,E]
#define OUT_LOGITS 0
#define OUT_VALUES (BB*NA)
#define OUT_MEM    (BB*NA + BB)

// ---- workspace layout ----
// fp32 regions (float offsets)
#define WS_H    0
#define WS_Q    (WS_H + BB*EE)
#define WS_R    (WS_Q + BB*EE)
#define WS_B16  (WS_R + BB*NH*EE)
// bf16 zone (ushort offsets from bf base)
#define U_QN    0
#define U_HN    (U_QN + BB*EE)
#define U_F1    (U_HN + BB*EE)
#define U_O     (U_F1 + BB*EE)
#define U_HB    (U_O  + BB*EE)
#define U_PV    (U_HB + BB*EE)
#define U_Z1A   (U_PV + BB*NH*EE)
#define U_Z2A   (U_Z1A + BB*HID)
#define U_Z1C   (U_Z2A + BB*HID)
#define U_Z2C   (U_Z1C + BB*HID)
#define U_OBSB  (U_Z2C + BB*HID)
#define U_END   (U_OBSB + BB*NOBS)
// int region (float offset)
#define WS_INT  (WS_B16 + (U_END + 1)/2)

#define WI_CNT  0
#define WI_OFF  8
#define WI_MODE 17
#define WI_ROWL 32

typedef __attribute__((ext_vector_type(8))) short bf16x8;
typedef __attribute__((ext_vector_type(4))) float f32x4;

__device__ __forceinline__ unsigned short f2bf(float f) {
  unsigned u = __float_as_uint(f);
  unsigned r = (u + 0x7fffu + ((u >> 16) & 1u)) >> 16;   // RNE
  return (unsigned short)r;
}
__device__ __forceinline__ float bf2f(unsigned short u) {
  return __uint_as_float(((unsigned)u) << 16);
}
__device__ __forceinline__ float bflo(unsigned u) { return __uint_as_float(u << 16); }
__device__ __forceinline__ float bfhi(unsigned u) { return __uint_as_float(u & 0xffff0000u); }

#define DPP_ADD(x, ctrl) \
  (x) += __int_as_float(__builtin_amdgcn_update_dpp(0, __float_as_int(x), (ctrl), 0xf, 0xf, true))

__device__ __forceinline__ float wave_sum(float x) {
  DPP_ADD(x, 0x121);
  DPP_ADD(x, 0x122);
  DPP_ADD(x, 0x124);
  DPP_ADD(x, 0x128);
  x += __shfl_xor(x, 16);
  x += __shfl_xor(x, 32);
  return x;
}

__device__ __forceinline__ float f4c(const float4 v, int c) {
  return c == 0 ? v.x : (c == 1 ? v.y : (c == 2 ? v.z : v.w));
}

// ---------------------------------------------------------------- prep
__global__ __launch_bounds__(256) void prep_k(const int* __restrict__ skills,
                                              const void* __restrict__ mask,
                                              int* __restrict__ wsI)
{
  __shared__ int cnt_s[TT];
  __shared__ int off_s[TT];
  const int tid = threadIdx.x;
  if (tid < TT) cnt_s[tid] = 0;
  __syncthreads();
  const int b0 = tid, b1i = tid + 256;
  const int t0 = skills[b0], t1 = skills[b1i];
  const int o0 = atomicAdd(&cnt_s[t0], 1);
  const int o1 = atomicAdd(&cnt_s[t1], 1);
  __syncthreads();
  if (tid == 0) {
    int off = 0;
    for (int t = 0; t < TT; ++t) {
      off_s[t] = off;
      wsI[WI_CNT + t] = cnt_s[t];
      wsI[WI_OFF + t] = off;
      off += cnt_s[t];
    }
    const unsigned char* m8 = (const unsigned char*)mask;
    const int w0 = *(const int*)mask;
    int mode = 0;
    if (m8[0] == 1 && m8[1] == 1 && m8[2] == 1 && m8[3] == 1) mode = 0;
    else if (w0 == 1) mode = 1;
    else if (w0 == 0x3f800000) mode = 2;
    wsI[WI_MODE] = mode;
  }
  __syncthreads();
  wsI[WI_ROWL + off_s[t0] + o0] = b0;
  wsI[WI_ROWL + off_s[t1] + o1] = b1i;
}

// ---------------------------------------------------------------- fp32 -> bf16 cvt
__global__ __launch_bounds__(256) void cvt_k(const float* __restrict__ src,
                                             unsigned short* __restrict__ dst)
{
  const int i = (blockIdx.x * 256 + threadIdx.x) * 4;
  const float4 v = *(const float4*)(src + i);
  uint2 p;
  p.x = (unsigned)f2bf(v.x) | ((unsigned)f2bf(v.y) << 16);
  p.y = (unsigned)f2bf(v.z) | ((unsigned)f2bf(v.w) << 16);
  *(uint2*)(dst + i) = p;
}

// ---------------------------------------------------------------- layernorm (fp32 in, bf16 out)
template<bool MEMOUT>
__global__ __launch_bounds__(256) void ln_k(const float* __restrict__ src,
                                            unsigned short* __restrict__ dst,
                                            const float* __restrict__ sp,
                                            const float* __restrict__ bp,
                                            const int* __restrict__ skills,
                                            float* __restrict__ memout, int l)
{
  const int b = blockIdx.x, tid = threadIdx.x;
  const int t = skills[b];
  const float x0 = src[(size_t)b*EE + tid];
  const float x1 = src[(size_t)b*EE + tid + 256];
  if (MEMOUT) {
    memout[((size_t)b*LLAY + l)*EE + tid] = x0;
    memout[((size_t)b*LLAY + l)*EE + tid + 256] = x1;
  }
  __shared__ float rs[4], rq[4];
  float s = wave_sum(x0 + x1);
  float q = wave_sum(x0*x0 + x1*x1);
  const int wvi = tid >> 6, lane = tid & 63;
  if (lane == 0) { rs[wvi] = s; rq[wvi] = q; }
  __syncthreads();
  const float S = rs[0] + rs[1] + rs[2] + rs[3];
  const float Q = rq[0] + rq[1] + rq[2] + rq[3];
  const float mu = S * (1.f/EE);
  const float inv = rsqrtf(Q*(1.f/EE) - mu*mu + 1e-6f);
  const size_t pb = ((size_t)t*LLAY + l)*EE;
  dst[(size_t)b*EE + tid]       = f2bf((x0 - mu)*inv*sp[pb + tid]       + bp[pb + tid]);
  dst[(size_t)b*EE + tid + 256] = f2bf((x1 - mu)*inv*sp[pb + tid + 256] + bp[pb + tid + 256]);
}

// ---------------------------------------------------------------- MFMA grouped GEMM
// C[row, jbase+n] = act(A[row,:] @ W[t][:, jbase+n] + bias) (+res)
// A bf16 row-major (rows gathered by task); W fp32 [K][N], converted inline.
// block: 256 thr = 4 waves; tile 32 rows x 64 cols; BK=64.
// Operand swap: W^T chunks as MFMA A-operand (rows=n), activations as
// B-operand (cols=m). D: lane&15 = m, (lane>>4)*4+reg = n.
template<bool RELU, bool HASBIAS, bool HASRES, bool OUTBF, bool HEADA>
__global__ __launch_bounds__(256) void mg_k(const unsigned short* __restrict__ A, int lda,
                                            const float* __restrict__ W, long wStride, long wOff,
                                            int K, int N,
                                            const float* __restrict__ bias, int bStride, int bOff,
                                            const float* __restrict__ res, int ldres,
                                            void* __restrict__ Cp, int ldc,
                                            const int* __restrict__ wsI)
{
  const int t = blockIdx.z;
  const int cnt = wsI[WI_CNT + t];
  const int rb = blockIdx.y * 32;
  if (cnt == 0 || rb >= cnt) return;
  const int off = wsI[WI_OFF + t];
  const int* rowl = wsI + WI_ROWL + off;
  const int tid = threadIdx.x;
  const int lane = tid & 63, w = tid >> 6;
  const int jbase = blockIdx.x * 64;
  const float* Wt = W + (size_t)t*wStride + wOff;

  __shared__ int rows_s[32];
  __shared__ __align__(16) unsigned short Alds[8][32][8];  // [kchunk][m][k&7]
  __shared__ __align__(16) unsigned short Wlds[8][64][8];  // [kchunk][n][k&7]

  if (tid < 32) rows_s[tid] = rowl[min(rb + tid, cnt - 1)];
  __syncthreads();

  const int wn = w & 1, wm = w >> 1;     // wave tile: rows wm*16.., cols wn*32..
  const int l15 = lane & 15, l4 = lane >> 4;

  f32x4 acc[2] = {{0.f,0.f,0.f,0.f},{0.f,0.f,0.f,0.f}};

  // A staging: thread -> (m = tid>>3, kchunk = tid&7), one 16B copy per k-step
  const int am = tid >> 3, ac = tid & 7;
  const size_t abase = (size_t)rows_s[am]*lda + (HEADA ? (size_t)(jbase >> 6)*EE : 0);
  // W staging: units (n = tid&63, kchunk = w + u*4)
  const int sn = tid & 63;

  for (int k0 = 0; k0 < K; k0 += 64) {
    // stage A (bf16 copy)
    *(uint4*)&Alds[ac][am][0] = *(const uint4*)(A + abase + k0 + ac*8);
    // stage W (fp32 -> bf16, k-packed)
    #pragma unroll
    for (int u = 0; u < 2; ++u) {
      const int kc = w + u*4;
      const float* wp = Wt + (size_t)(k0 + kc*8)*N + jbase + sn;
      float f[8];
      #pragma unroll
      for (int kk = 0; kk < 8; ++kk) f[kk] = wp[(size_t)kk*N];
      unsigned short tmp[8];
      #pragma unroll
      for (int kk = 0; kk < 8; ++kk) tmp[kk] = f2bf(f[kk]);
      *(uint4*)&Wlds[kc][sn][0] = *(uint4*)tmp;
    }
    __syncthreads();
    #pragma unroll
    for (int ks = 0; ks < 2; ++ks) {
      const bf16x8 bfr = *(const bf16x8*)&Alds[ks*4 + l4][wm*16 + l15][0];
      #pragma unroll
      for (int nf = 0; nf < 2; ++nf) {
        const bf16x8 afr = *(const bf16x8*)&Wlds[ks*4 + l4][wn*32 + nf*16 + l15][0];
        acc[nf] = __builtin_amdgcn_mfma_f32_16x16x32_bf16(afr, bfr, acc[nf], 0, 0, 0);
      }
    }
    __syncthreads();
  }

  // epilogue
  const int mrow = wm*16 + l15;
  if (rb + mrow < cnt) {
    const int row = rows_s[mrow];
    #pragma unroll
    for (int nf = 0; nf < 2; ++nf) {
      const int nb = jbase + wn*32 + nf*16 + l4*4;
      float vv[4];
      float4 bv, rv;
      if (HASBIAS) bv = *(const float4*)(bias + (size_t)t*bStride + bOff + nb);
      if (HASRES)  rv = *(const float4*)(res + (size_t)row*ldres + nb);
      #pragma unroll
      for (int c = 0; c < 4; ++c) {
        float x = acc[nf][c];
        if (HASBIAS) x += f4c(bv, c);
        if (RELU)    x = fmaxf(x, 0.f);
        if (HASRES)  x += f4c(rv, c);
        vv[c] = x;
      }
      if (OUTBF) {
        uint2 p;
        p.x = (unsigned)f2bf(vv[0]) | ((unsigned)f2bf(vv[1]) << 16);
        p.y = (unsigned)f2bf(vv[2]) | ((unsigned)f2bf(vv[3]) << 16);
        *(uint2*)((unsigned short*)Cp + (size_t)row*ldc + nb) = p;
      } else {
        *(float4*)((float*)Cp + (size_t)row*ldc + nb) = make_float4(vv[0], vv[1], vv[2], vv[3]);
      }
    }
  }
}

// ---------------------------------------------------------------- R kernel (fp32)
// R[b,h,e] = sum_d Wk[e, h*64+d] * q[b, h*64+d]
__global__ __launch_bounds__(256) void r_k(const float* __restrict__ q_ws,
                                           const float* __restrict__ Wk,
                                           float* __restrict__ R_ws,
                                           const int* __restrict__ wsI, int l)
{
  const int t = blockIdx.z;
  const int cnt = wsI[WI_CNT + t];
  if (cnt == 0) return;
  const int off = wsI[WI_OFF + t];
  const int* rowl = wsI + WI_ROWL + off;
  const int et = blockIdx.x >> 3, h = blockIdx.x & 7;
  const int tid = threadIdx.x;
  const int jl = tid & 63, rgrp = tid >> 6;
  const float* Wt = Wk + ((size_t)t*LLAY + l)*EE*EE;

  __shared__ __align__(16) float Qt[32*68];
  __shared__ float Wl[64*68];
  __shared__ int rows_s[32];

  #pragma unroll 4
  for (int i = 0; i < 16; ++i) {
    const int lin = i*256 + tid;
    const int e = lin >> 6, d = lin & 63;
    Wl[d*68 + e] = Wt[(size_t)(et*64 + e)*EE + h*64 + d];
  }

  for (int rb = blockIdx.y*32; rb < cnt; rb += 128) {
    __syncthreads();
    if (tid < 32) rows_s[tid] = rowl[min(rb + tid, cnt - 1)];
    __syncthreads();
    {
      const int rr = tid >> 3, d8 = (tid & 7)*8;
      const float* qp = q_ws + (size_t)rows_s[rr]*EE + h*64 + d8;
      *(float4*)&Qt[rr*68 + d8]     = *(const float4*)qp;
      *(float4*)&Qt[rr*68 + d8 + 4] = *(const float4*)(qp + 4);
    }
    __syncthreads();
    float acc[8];
    #pragma unroll
    for (int rr = 0; rr < 8; ++rr) acc[rr] = 0.f;
    #pragma unroll
    for (int d4 = 0; d4 < 64; d4 += 4) {
      float4 a[8];
      #pragma unroll
      for (int rr = 0; rr < 8; ++rr)
        a[rr] = *(const float4*)&Qt[(rgrp*8 + rr)*68 + d4];
      #pragma unroll
      for (int c = 0; c < 4; ++c) {
        const float wv = Wl[(d4 + c)*68 + jl];
        #pragma unroll
        for (int rr = 0; rr < 8; ++rr) acc[rr] += f4c(a[rr], c)*wv;
      }
    }
    #pragma unroll
    for (int rr = 0; rr < 8; ++rr) {
      const int r = rb + rgrp*8 + rr;
      if (r < cnt)
        R_ws[((size_t)rows_s[rgrp*8 + rr]*NH + h)*EE + et*64 + jl] = acc[rr];
    }
  }
}

// ---------------------------------------------------------------- attention
// per (b,l): low-rank scores, masked softmax with analytic LN folding,
// PV[b,h,e] (bf16) = normalized sum_m p*kn[m,e].
__global__ __launch_bounds__(256) void attn_k(const float* __restrict__ mem,
                                              const unsigned short* __restrict__ qn,
                                              const float* __restrict__ R_ws,
                                              const float* __restrict__ ln1s,
                                              const float* __restrict__ ln1b,
                                              const void* __restrict__ mask,
                                              const int* __restrict__ skills,
                                              const int* __restrict__ wsI,
                                              unsigned short* __restrict__ PV, int l)
{
  const int b = blockIdx.x, tid = threadIdx.x;
  const int wvi = tid >> 6, lane = tid & 63;
  const int t = skills[b];
  const int mode = wsI[WI_MODE];

  __shared__ __align__(16) float qn_l[EE];
  __shared__ __align__(16) float w_s[NH][132];
  __shared__ float mu_s[MM], inv_s[MM];
  __shared__ float hsS[NH], hsA[NH], hsP[NH], hspex[NH];

  for (int i = tid; i < EE; i += 256) qn_l[i] = bf2f(qn[(size_t)b*EE + i]);

  const int e8 = lane*8;
  const float* s1p = ln1s + ((size_t)t*LLAY + l)*EE;
  const float* b1p = ln1b + ((size_t)t*LLAY + l)*EE;
  float s1v[8], b1v[8], qnv[8];
  *(float4*)&s1v[0] = *(const float4*)(s1p + e8);
  *(float4*)&s1v[4] = *(const float4*)(s1p + e8 + 4);
  *(float4*)&b1v[0] = *(const float4*)(b1p + e8);
  *(float4*)&b1v[4] = *(const float4*)(b1p + e8 + 4);
  {
    const uint4 qu = *(const uint4*)(qn + (size_t)b*EE + e8);
    qnv[0] = bflo(qu.x); qnv[1] = bfhi(qu.x);
    qnv[2] = bflo(qu.y); qnv[3] = bfhi(qu.y);
    qnv[4] = bflo(qu.z); qnv[5] = bfhi(qu.z);
    qnv[6] = bflo(qu.w); qnv[7] = bfhi(qu.w);
  }

  const float scale = 0.125f;  // 1/sqrt(64)
  float rp[NH][8];
  float SR[NH], BR[NH], SE[NH];
  #pragma unroll
  for (int h = 0; h < NH; ++h) {
    float rv[8];
    *(float4*)&rv[0] = *(const float4*)(R_ws + ((size_t)b*NH + h)*EE + e8);
    *(float4*)&rv[4] = *(const float4*)(R_ws + ((size_t)b*NH + h)*EE + e8 + 4);
    float pr = 0.f, pb = 0.f, ps = 0.f;
    #pragma unroll
    for (int j = 0; j < 8; ++j) {
      const float r = rv[j]*scale;
      const float x = r*s1v[j];
      rp[h][j] = x;
      pr += x; pb += b1v[j]*r; ps += qnv[j]*r;
    }
    SR[h] = wave_sum(pr);
    BR[h] = wave_sum(pb);
    SE[h] = wave_sum(ps);
  }

  // phase A: stream memory rows, score = inv*dot(x,rp) - mu*inv*SR + BR
  for (int m = wvi; m < MM; m += 4) {
    const float* rowp = mem + (((size_t)b*LLAY + l)*MM + m)*EE;
    float xv[8];
    *(float4*)&xv[0] = *(const float4*)(rowp + e8);
    *(float4*)&xv[4] = *(const float4*)(rowp + e8 + 4);
    float s = 0.f, q = 0.f;
    #pragma unroll
    for (int j = 0; j < 8; ++j) { s += xv[j]; q += xv[j]*xv[j]; }
    const float S = wave_sum(s);
    const float Q = wave_sum(q);
    const float muv = S*(1.f/EE);
    const float invv = rsqrtf(Q*(1.f/EE) - muv*muv + 1e-6f);
    float dd[NH];
    #pragma unroll
    for (int h = 0; h < NH; ++h) {
      float a = 0.f;
      #pragma unroll
      for (int j = 0; j < 8; ++j) a += xv[j]*rp[h][j];
      dd[h] = wave_sum(a);
    }
    bool valid;
    if (mode == 0)      valid = ((const unsigned char*)mask)[(size_t)b*MM + m] != 0;
    else if (mode == 1) valid = ((const int*)mask)[(size_t)b*MM + m] != 0;
    else                valid = ((const float*)mask)[(size_t)b*MM + m] != 0.f;
    if (lane == 0) {
      mu_s[m] = muv; inv_s[m] = invv;
      #pragma unroll
      for (int h = 0; h < NH; ++h)
        w_s[h][m] = valid ? (invv*dd[h] - muv*invv*SR[h] + BR[h]) : -1e30f;
    }
  }
  if (tid == 0) {
    #pragma unroll
    for (int h = 0; h < NH; ++h) w_s[h][MM] = SE[h];
  }
  __syncthreads();

  // softmax per head over 129 entries
  {
    const int h = tid >> 5, li = tid & 31;
    const float v0 = w_s[h][li], v1 = w_s[h][li+32], v2 = w_s[h][li+64], v3 = w_s[h][li+96];
    const float ve = (li == 0) ? w_s[h][MM] : -3e38f;
    float mx = fmaxf(fmaxf(fmaxf(v0, v1), fmaxf(v2, v3)), ve);
    #pragma unroll
    for (int o = 16; o; o >>= 1) mx = fmaxf(mx, __shfl_xor(mx, o));
    const float i0 = inv_s[li], i1 = inv_s[li+32], i2 = inv_s[li+64], i3 = inv_s[li+96];
    const float m0 = mu_s[li], m1 = mu_s[li+32], m2 = mu_s[li+64], m3 = mu_s[li+96];
    const float p0 = __expf(v0 - mx), p1 = __expf(v1 - mx);
    const float p2 = __expf(v2 - mx), p3 = __expf(v3 - mx);
    const float pe = (li == 0) ? __expf(ve - mx) : 0.f;
    float Sp = p0 + p1 + p2 + p3 + pe;
    float Ap = p0*m0*i0 + p1*m1*i1 + p2*m2*i2 + p3*m3*i3;
    float Pp = p0 + p1 + p2 + p3;
    w_s[h][li]    = p0*i0;
    w_s[h][li+32] = p1*i1;
    w_s[h][li+64] = p2*i2;
    w_s[h][li+96] = p3*i3;
    #pragma unroll
    for (int o = 16; o; o >>= 1) {
      Sp += __shfl_xor(Sp, o);
      Ap += __shfl_xor(Ap, o);
      Pp += __shfl_xor(Pp, o);
    }
    if (li == 0) { hsS[h] = Sp; hsA[h] = Ap; hsP[h] = Pp; hspex[h] = pe; }
  }
  __syncthreads();

  // phase B: U[h,e] = sum_m (p*inv)[m,h]*x[m,e]; fold LN terms, normalize
  const int e0 = wvi*128 + lane*2;
  const float s1x = s1p[e0], s1y = s1p[e0+1];
  const float b1x = b1p[e0], b1y = b1p[e0+1];
  const float qx = qn_l[e0], qy = qn_l[e0+1];
  float accx[NH], accy[NH];
  #pragma unroll
  for (int h = 0; h < NH; ++h) { accx[h] = 0.f; accy[h] = 0.f; }
  const float* bp2 = mem + ((size_t)b*LLAY + l)*MM*EE + e0;
  for (int m4 = 0; m4 < MM; m4 += 4) {
    float4 wv4[NH];
    #pragma unroll
    for (int h = 0; h < NH; ++h) wv4[h] = *(const float4*)&w_s[h][m4];
    #pragma unroll
    for (int c = 0; c < 4; ++c) {
      const float2 x2 = *(const float2*)(bp2 + (size_t)(m4 + c)*EE);
      #pragma unroll
      for (int h = 0; h < NH; ++h) {
        const float wv = f4c(wv4[h], c);
        accx[h] += wv*x2.x;
        accy[h] += wv*x2.y;
      }
    }
  }
  #pragma unroll
  for (int h = 0; h < NH; ++h) {
    const float is = 1.f/hsS[h];
    const float px = (s1x*(accx[h] - hsA[h]) + b1x*hsP[h] + hspex[h]*qx)*is;
    const float py = (s1y*(accy[h] - hsA[h]) + b1y*hsP[h] + hspex[h]*qy)*is;
    const unsigned pk = (unsigned)f2bf(px) | ((unsigned)f2bf(py) << 16);
    *(unsigned*)(PV + ((size_t)b*NH + h)*EE + e0) = pk;
  }
}

// ---------------------------------------------------------------- head
__global__ __launch_bounds__(256) void head_k(const unsigned short* __restrict__ z2a,
                                              const unsigned short* __restrict__ z2c,
                                              const float* __restrict__ aW3,
                                              const float* __restrict__ ab3,
                                              const float* __restrict__ cW3,
                                              const float* __restrict__ cb3,
                                              const int* __restrict__ skills,
                                              float* __restrict__ out)
{
  const int b = blockIdx.x, tid = threadIdx.x;
  const int t = skills[b];
  __shared__ float za[HID], zc[HID];
  __shared__ float red[16][17];
  __shared__ float redv[4];
  for (int i = tid; i < HID; i += 256) {
    za[i] = bf2f(z2a[(size_t)b*HID + i]);
    zc[i] = bf2f(z2c[(size_t)b*HID + i]);
  }
  __syncthreads();
  {
    const int j = tid & 15, grp = tid >> 4;
    const float* w = aW3 + (size_t)t*HID*NA;
    float p = 0.f;
    for (int i = grp*64; i < grp*64 + 64; ++i) p += za[i]*w[(size_t)i*NA + j];
    red[grp][j] = p;
  }
  float pvv = 0.f;
  {
    const float* w = cW3 + (size_t)t*HID;
    for (int i = tid; i < HID; i += 256) pvv += zc[i]*w[i];
  }
  pvv = wave_sum(pvv);
  const int wvi = tid >> 6, lane = tid & 63;
  if (lane == 0) redv[wvi] = pvv;
  __syncthreads();
  if (tid < 16) {
    float v = ab3[(size_t)t*NA + tid];
    #pragma unroll
    for (int g = 0; g < 16; ++g) v += red[g][tid];
    out[OUT_LOGITS + (size_t)b*NA + tid] = v;
  }
  if (tid == 0)
    out[OUT_VALUES + b] = cb3[t] + redv[0] + redv[1] + redv[2] + redv[3];
}

// ---------------------------------------------------------------- launch
extern "C" void kernel_launch(void* const* d_in, const int* in_sizes, int n_in,
                              void* d_out, int out_size, void* d_ws, size_t ws_size,
                              hipStream_t stream)
{
  (void)in_sizes; (void)n_in; (void)out_size; (void)ws_size;
  const float* memories = (const float*)d_in[0];
  const float* obs   = (const float*)d_in[1];
  const float* We    = (const float*)d_in[2];
  const float* be    = (const float*)d_in[3];
  const float* Wq    = (const float*)d_in[4];
  const float* Wk    = (const float*)d_in[5];
  const float* Wv    = (const float*)d_in[6];
  const float* Wo    = (const float*)d_in[7];
  const float* bo    = (const float*)d_in[8];
  const float* W1    = (const float*)d_in[9];
  const float* b1    = (const float*)d_in[10];
  const float* W2    = (const float*)d_in[11];
  const float* b2    = (const float*)d_in[12];
  const float* ln1s  = (const float*)d_in[13];
  const float* ln1b  = (const float*)d_in[14];
  const float* ln2s  = (const float*)d_in[15];
  const float* ln2b  = (const float*)d_in[16];
  const float* aW1   = (const float*)d_in[17];
  const float* ab1   = (const float*)d_in[18];
  const float* aW2   = (const float*)d_in[19];
  const float* ab2   = (const float*)d_in[20];
  const float* aW3   = (const float*)d_in[21];
  const float* ab3   = (const float*)d_in[22];
  const float* cW1   = (const float*)d_in[23];
  const float* cb1   = (const float*)d_in[24];
  const float* cW2   = (const float*)d_in[25];
  const float* cb2   = (const float*)d_in[26];
  const float* cW3   = (const float*)d_in[27];
  const float* cb3   = (const float*)d_in[28];
  const int*   skills= (const int*)d_in[29];
  const void*  mask  = d_in[30];

  float* ws  = (float*)d_ws;
  float* out = (float*)d_out;
  float* h   = ws + WS_H;
  float* q   = ws + WS_Q;
  float* R   = ws + WS_R;
  unsigned short* bf = (unsigned short*)(ws + WS_B16);
  unsigned short* qn   = bf + U_QN;
  unsigned short* hn   = bf + U_HN;
  unsigned short* f1   = bf + U_F1;
  unsigned short* o    = bf + U_O;
  unsigned short* hb   = bf + U_HB;
  unsigned short* PV   = bf + U_PV;
  unsigned short* z1a  = bf + U_Z1A;
  unsigned short* z2a  = bf + U_Z2A;
  unsigned short* z1c  = bf + U_Z1C;
  unsigned short* z2c  = bf + U_Z2C;
  unsigned short* obsb = bf + U_OBSB;
  int* wsI = (int*)(ws + WS_INT);

  prep_k<<<1, 256, 0, stream>>>(skills, mask, wsI);
  cvt_k<<<BB*NOBS/1024, 256, 0, stream>>>(obs, obsb);

  // h = obs @ We[t] + be[t]   (fp32 out)
  mg_k<false,true,false,false,false><<<dim3(EE/64,16,TT), 256, 0, stream>>>(
      obsb, NOBS, We, (long)NOBS*EE, 0, NOBS, EE, be, EE, 0,
      nullptr, 0, h, EE, wsI);

  for (int l = 0; l < LLAY; ++l) {
    const long wOff = (long)l*EE*EE;
    ln_k<true><<<BB, 256, 0, stream>>>(h, qn, ln1s, ln1b, skills, out + OUT_MEM, l);
    // q = qn @ Wq  (fp32 out)
    mg_k<false,false,false,false,false><<<dim3(EE/64,16,TT), 256, 0, stream>>>(
        qn, EE, Wq, (long)LLAY*EE*EE, wOff, EE, EE, nullptr, 0, 0,
        nullptr, 0, q, EE, wsI);
    r_k<<<dim3(64,4,TT), 256, 0, stream>>>(q, Wk, R, wsI, l);
    attn_k<<<BB, 256, 0, stream>>>(memories, qn, R, ln1s, ln1b, mask, skills, wsI, PV, l);
    // o = PV @ Wv  (per-head A slice, bf16 out)
    mg_k<false,false,false,true,true><<<dim3(EE/64,16,TT), 256, 0, stream>>>(
        PV, NH*EE, Wv, (long)LLAY*EE*EE, wOff, EE, EE, nullptr, 0, 0,
        nullptr, 0, o, EE, wsI);
    // h = h + o @ Wo + bo  (fp32 out, residual)
    mg_k<false,true,true,false,false><<<dim3(EE/64,16,TT), 256, 0, stream>>>(
        o, EE, Wo, (long)LLAY*EE*EE, wOff, EE, EE, bo, LLAY*EE, l*EE,
        h, EE, h, EE, wsI);
    ln_k<false><<<BB, 256, 0, stream>>>(h, hn, ln2s, ln2b, skills, nullptr, l);
    // f1 = relu(hn @ W1 + b1)  (bf16 out)
    mg_k<true,true,false,true,false><<<dim3(EE/64,16,TT), 256, 0, stream>>>(
        hn, EE, W1, (long)LLAY*EE*EE, wOff, EE, EE, b1, LLAY*EE, l*EE,
        nullptr, 0, f1, EE, wsI);
    // h = h + f1 @ W2 + b2  (fp32 out, residual)
    mg_k<false,true,true,false,false><<<dim3(EE/64,16,TT), 256, 0, stream>>>(
        f1, EE, W2, (long)LLAY*EE*EE, wOff, EE, EE, b2, LLAY*EE, l*EE,
        h, EE, h, EE, wsI);
  }

  cvt_k<<<BB*EE/1024, 256, 0, stream>>>(h, hb);

  // actor / critic MLPs (bf16)
  mg_k<true,true,false,true,false><<<dim3(HID/64,16,TT), 256, 0, stream>>>(
      hb, EE, aW1, (long)EE*HID, 0, EE, HID, ab1, HID, 0, nullptr, 0, z1a, HID, wsI);
  mg_k<true,true,false,true,false><<<dim3(HID/64,16,TT), 256, 0, stream>>>(
      z1a, HID, aW2, (long)HID*HID, 0, HID, HID, ab2, HID, 0, nullptr, 0, z2a, HID, wsI);
  mg_k<true,true,false,true,false><<<dim3(HID/64,16,TT), 256, 0, stream>>>(
      hb, EE, cW1, (long)EE*HID, 0, EE, HID, cb1, HID, 0, nullptr, 0, z1c, HID, wsI);
  mg_k<true,true,false,true,false><<<dim3(HID/64,16,TT), 256, 0, stream>>>(
      z1c, HID, cW2, (long)HID*HID, 0, HID, HID, cb2, HID, 0, nullptr, 0, z2c, HID, wsI);

  head_k<<<BB, 256, 0, stream>>>(z2a, z2c, aW3, ab3, cW3, cb3, skills, out);
}